// Round 1
// baseline (1626.328 us; speedup 1.0000x reference)
//
#include <hip/hip_runtime.h>
#include <hip/hip_fp16.h>
#include <stdint.h>
#include <stddef.h>

// ---------------------------------------------------------------------------
// fp8-fake-quant linear: out = clip(x/s_in, +-448) @ W^T * (s_in*s_w) + bias
// M=8192 K=4096 N=16384 (derived at runtime from in_sizes; tiles must divide).
// Strategy: cast both operands to f16 (error budget analyzed: ~2e-3 absmax
// vs 7.5e-2 threshold), then m97-structure MFMA GEMM (128x128 tile, BK=32,
// 16x16x32 f16 MFMA, global_load_lds width-16, LDS double buffer).
// ---------------------------------------------------------------------------

typedef _Float16 half8 __attribute__((ext_vector_type(8)));
typedef _Float16 half4v __attribute__((ext_vector_type(4)));
typedef float f32x4 __attribute__((ext_vector_type(4)));

#define BM 128
#define BN 128
#define BK 32
#define FP8MAX 448.0f

__device__ __forceinline__ void gload_lds16(const _Float16* g, _Float16* lds) {
  __builtin_amdgcn_global_load_lds(
      (const __attribute__((address_space(1))) uint32_t*)g,
      (__attribute__((address_space(3))) uint32_t*)lds, 16, 0, 0);
}

// ---- pass 1a: x_q = (f16) clip(x / s_in, +-448) ---------------------------
__global__ void cvt_x_kernel(const float* __restrict__ x, _Float16* __restrict__ xq,
                             const float* __restrict__ s_ptr, long n4) {
  float inv = 1.0f / s_ptr[0];
  long i = (long)blockIdx.x * blockDim.x + threadIdx.x;
  long stride = (long)gridDim.x * blockDim.x;
  const float4* x4 = (const float4*)x;
  for (long j = i; j < n4; j += stride) {
    float4 v = x4[j];
    half4v h;
    h[0] = (_Float16)fminf(fmaxf(v.x * inv, -FP8MAX), FP8MAX);
    h[1] = (_Float16)fminf(fmaxf(v.y * inv, -FP8MAX), FP8MAX);
    h[2] = (_Float16)fminf(fmaxf(v.z * inv, -FP8MAX), FP8MAX);
    h[3] = (_Float16)fminf(fmaxf(v.w * inv, -FP8MAX), FP8MAX);
    *(half4v*)(xq + j * 4) = h;
  }
}

// ---- pass 1b: w_q = (f16) w ------------------------------------------------
__global__ void cvt_w_kernel(const float* __restrict__ w, _Float16* __restrict__ wq,
                             long n4) {
  long i = (long)blockIdx.x * blockDim.x + threadIdx.x;
  long stride = (long)gridDim.x * blockDim.x;
  const float4* w4 = (const float4*)w;
  for (long j = i; j < n4; j += stride) {
    float4 v = w4[j];
    half4v h;
    h[0] = (_Float16)v.x; h[1] = (_Float16)v.y;
    h[2] = (_Float16)v.z; h[3] = (_Float16)v.w;
    *(half4v*)(wq + j * 4) = h;
  }
}

// ---- pass 2: GEMM ----------------------------------------------------------
// FUSED=false: A16/B16 are pre-converted f16 (fast path, global_load_lds).
// FUSED=true : convert f32 -> f16 on the fly via register staging (ws too small).
template <bool FUSED>
__global__ __launch_bounds__(256, 2)
void gemm_f16_kernel(const _Float16* __restrict__ A16, const _Float16* __restrict__ B16,
                     const float* __restrict__ Af32, const float* __restrict__ Bf32,
                     const float* __restrict__ bias,
                     const float* __restrict__ is_ptr, const float* __restrict__ ws_ptr,
                     float* __restrict__ out, int M, int N, int K) {
  __shared__ _Float16 sA[2][BM * BK];
  __shared__ _Float16 sB[2][BN * BK];

  const int nbn = N / BN;
  const int nwg = gridDim.x;
  int wg = blockIdx.x;
  if ((nwg & 7) == 0) {               // bijective XCD swizzle (8 XCDs)
    int q = nwg >> 3;
    wg = (wg & 7) * q + (wg >> 3);
  }
  const int bm = wg / nbn, bn = wg % nbn;
  const int brow = bm * BM, bcol = bn * BN;

  const int t = threadIdx.x;
  const int lane = t & 63;
  const int w = t >> 6;          // wave id 0..3
  const int wr = w >> 1;         // wave row 0..1 (64 rows each)
  const int wc = w & 1;          // wave col 0..1 (64 cols each)

  float ainv = FUSED ? (1.0f / is_ptr[0]) : 0.0f;

  f32x4 acc[4][4] = {};

  // ---- staging: tile is [128 rows][32 k] f16 row-major = 512 chunks of 16B.
  auto stage = [&](int buf, int kt) {
    if constexpr (!FUSED) {
#pragma unroll
      for (int i = 0; i < 2; ++i) {
        int c = i * 256 + t;                 // chunk 0..511
        int m = c >> 2, k0 = (c & 3) * 8;
        gload_lds16(A16 + (size_t)(brow + m) * K + kt + k0,
                    &sA[buf][(i * 256 + w * 64) * 8]);
      }
#pragma unroll
      for (int i = 0; i < 2; ++i) {
        int c = i * 256 + t;
        int m = c >> 2, k0 = (c & 3) * 8;
        gload_lds16(B16 + (size_t)(bcol + m) * K + kt + k0,
                    &sB[buf][(i * 256 + w * 64) * 8]);
      }
    } else {
#pragma unroll
      for (int i = 0; i < 2; ++i) {
        int c = i * 256 + t;
        int m = c >> 2, k0 = (c & 3) * 8;
        const float* g = Af32 + (size_t)(brow + m) * K + kt + k0;
        float4 v0 = *(const float4*)g;
        float4 v1 = *(const float4*)(g + 4);
        half8 h;
        h[0] = (_Float16)fminf(fmaxf(v0.x * ainv, -FP8MAX), FP8MAX);
        h[1] = (_Float16)fminf(fmaxf(v0.y * ainv, -FP8MAX), FP8MAX);
        h[2] = (_Float16)fminf(fmaxf(v0.z * ainv, -FP8MAX), FP8MAX);
        h[3] = (_Float16)fminf(fmaxf(v0.w * ainv, -FP8MAX), FP8MAX);
        h[4] = (_Float16)fminf(fmaxf(v1.x * ainv, -FP8MAX), FP8MAX);
        h[5] = (_Float16)fminf(fmaxf(v1.y * ainv, -FP8MAX), FP8MAX);
        h[6] = (_Float16)fminf(fmaxf(v1.z * ainv, -FP8MAX), FP8MAX);
        h[7] = (_Float16)fminf(fmaxf(v1.w * ainv, -FP8MAX), FP8MAX);
        *(half8*)&sA[buf][c * 8] = h;
      }
#pragma unroll
      for (int i = 0; i < 2; ++i) {
        int c = i * 256 + t;
        int m = c >> 2, k0 = (c & 3) * 8;
        const float* g = Bf32 + (size_t)(bcol + m) * K + kt + k0;
        float4 v0 = *(const float4*)g;
        float4 v1 = *(const float4*)(g + 4);
        half8 h;
        h[0] = (_Float16)v0.x; h[1] = (_Float16)v0.y;
        h[2] = (_Float16)v0.z; h[3] = (_Float16)v0.w;
        h[4] = (_Float16)v1.x; h[5] = (_Float16)v1.y;
        h[6] = (_Float16)v1.z; h[7] = (_Float16)v1.w;
        *(half8*)&sB[buf][c * 8] = h;
      }
    }
  };

  stage(0, 0);
  asm volatile("s_waitcnt vmcnt(0)" ::: "memory");
  __syncthreads();

  int cur = 0;
  for (int kt = 0; kt < K; kt += BK) {
    if (kt + BK < K) stage(cur ^ 1, kt + BK);

    // fragment reads: row = lane&15 (+m*16), k0 = (lane>>4)*8 -> ds_read_b128
    half8 a[4], b[4];
    const _Float16* pA = &sA[cur][(wr * 64 + (lane & 15)) * BK + (lane >> 4) * 8];
    const _Float16* pB = &sB[cur][(wc * 64 + (lane & 15)) * BK + (lane >> 4) * 8];
#pragma unroll
    for (int m = 0; m < 4; ++m) a[m] = *(const half8*)(pA + m * 16 * BK);
#pragma unroll
    for (int n = 0; n < 4; ++n) b[n] = *(const half8*)(pB + n * 16 * BK);

#pragma unroll
    for (int m = 0; m < 4; ++m)
#pragma unroll
      for (int n = 0; n < 4; ++n)
        acc[m][n] = __builtin_amdgcn_mfma_f32_16x16x32_f16(a[m], b[n], acc[m][n], 0, 0, 0);

    asm volatile("s_waitcnt vmcnt(0)" ::: "memory");
    __syncthreads();
    cur ^= 1;
  }

  // ---- epilogue: C/D layout (16x16): col = lane&15, row = (lane>>4)*4 + r
  float s = is_ptr[0] * ws_ptr[0];
  const int orow = brow + wr * 64;
  const int ocol = bcol + wc * 64;
#pragma unroll
  for (int n = 0; n < 4; ++n) {
    int col = ocol + n * 16 + (lane & 15);
    float bv = bias[col];
#pragma unroll
    for (int m = 0; m < 4; ++m) {
      int row0 = orow + m * 16 + (lane >> 4) * 4;
#pragma unroll
      for (int r = 0; r < 4; ++r)
        out[(size_t)(row0 + r) * N + col] = acc[m][n][r] * s + bv;
    }
  }
}

// ---------------------------------------------------------------------------
extern "C" void kernel_launch(void* const* d_in, const int* in_sizes, int n_in,
                              void* d_out, int out_size, void* d_ws, size_t ws_size,
                              hipStream_t stream) {
  const float* x    = (const float*)d_in[0];
  const float* wgt  = (const float*)d_in[1];
  const float* bias = (const float*)d_in[2];
  const float* is   = (const float*)d_in[3];
  const float* wsc  = (const float*)d_in[4];
  float* out = (float*)d_out;

  const long x_n = in_sizes[0];
  const long w_n = in_sizes[1];
  const int  N   = in_sizes[2];
  const int  K   = (int)(w_n / N);
  const int  M   = (int)(x_n / K);

  const int nwg = (M / BM) * (N / BN);
  const size_t need = (size_t)(x_n + w_n) * sizeof(_Float16);

  if (ws_size >= need) {
    _Float16* xq = (_Float16*)d_ws;
    _Float16* wq = xq + x_n;
    cvt_x_kernel<<<2048, 256, 0, stream>>>(x, xq, is, x_n >> 2);
    cvt_w_kernel<<<2048, 256, 0, stream>>>(wgt, wq, w_n >> 2);
    gemm_f16_kernel<false><<<nwg, 256, 0, stream>>>(
        xq, wq, nullptr, nullptr, bias, is, wsc, out, M, N, K);
  } else {
    gemm_f16_kernel<true><<<nwg, 256, 0, stream>>>(
        nullptr, nullptr, x, wgt, bias, is, wsc, out, M, N, K);
  }
}

// Round 2
// 1502.707 us; speedup vs baseline: 1.0823x; 1.0823x over previous
//
#include <hip/hip_runtime.h>
#include <stdint.h>
#include <stddef.h>

// ---------------------------------------------------------------------------
// fp8-fake-quant linear: out = clip(x/s_in, +-448) @ W^T * (s_in*s_w) + bias
// M=8192 K=4096 N=16384. f16 operands (error budget ~2e-2 vs 7.5e-2 thr).
// Round 2: 256x256 tile, BK=64, 8 waves (2Mx4N), 8-phase K-loop with counted
// vmcnt(4) (T3+T4), setprio around MFMA clusters (T5), XCD swizzle (T1).
// Half-tiles are K-SPLIT (A-k0,B-k0,A-k1,B-k1; 16KiB each, 2 loads/thread),
// LDS [buf][ksub][256][32] so global_load_lds stays wave-linear and frag
// reads cover a contiguous 1KB/wave block (bank-even, no swizzle needed).
// In-flight invariant at tile start: {this tile k1} in flight (4 loads),
// everything older complete. vmcnt(4) at phase 2 (-> k1 ready for p3/p4) and
// phase 4 (-> next tile k0 ready). Never drains to 0 in the main loop.
// ---------------------------------------------------------------------------

typedef _Float16 half8 __attribute__((ext_vector_type(8)));
typedef _Float16 half4v __attribute__((ext_vector_type(4)));
typedef float f32x4 __attribute__((ext_vector_type(4)));

#define BM 256
#define BN 256
#define BK 64
#define FP8MAX 448.0f

__device__ __forceinline__ void gload_lds16(const _Float16* g, _Float16* lds) {
  __builtin_amdgcn_global_load_lds(
      (const __attribute__((address_space(1))) uint32_t*)g,
      (__attribute__((address_space(3))) uint32_t*)lds, 16, 0, 0);
}

#define BAR() asm volatile("s_barrier" ::: "memory")
#define WAIT_VM(N) asm volatile("s_waitcnt vmcnt(" #N ")" ::: "memory")

// 16 MFMA cluster (4 M-frags x 4 N-frags x K=32), setprio-wrapped (T5).
// ACC indices are compile-time constants (rule #20: no runtime acc indexing).
#define MFMA16(AF, BF, ACC) do {                                              \
  __builtin_amdgcn_s_setprio(1);                                             \
  _Pragma("unroll")                                                          \
  for (int m_ = 0; m_ < 4; ++m_) {                                           \
    _Pragma("unroll")                                                        \
    for (int n_ = 0; n_ < 4; ++n_)                                           \
      ACC[m_][n_] = __builtin_amdgcn_mfma_f32_16x16x32_f16(                  \
          AF[m_], BF[n_], ACC[m_][n_], 0, 0, 0);                             \
  }                                                                          \
  __builtin_amdgcn_s_setprio(0);                                             \
} while (0)

// ---- pass 1a: x_q = (f16) clip(x / s_in, +-448) ---------------------------
__global__ void cvt_x_kernel(const float* __restrict__ x, _Float16* __restrict__ xq,
                             const float* __restrict__ s_ptr, long n4) {
  float inv = 1.0f / s_ptr[0];
  long i = (long)blockIdx.x * blockDim.x + threadIdx.x;
  long stride = (long)gridDim.x * blockDim.x;
  const float4* x4 = (const float4*)x;
  for (long j = i; j < n4; j += stride) {
    float4 v = x4[j];
    half4v h;
    h[0] = (_Float16)fminf(fmaxf(v.x * inv, -FP8MAX), FP8MAX);
    h[1] = (_Float16)fminf(fmaxf(v.y * inv, -FP8MAX), FP8MAX);
    h[2] = (_Float16)fminf(fmaxf(v.z * inv, -FP8MAX), FP8MAX);
    h[3] = (_Float16)fminf(fmaxf(v.w * inv, -FP8MAX), FP8MAX);
    *(half4v*)(xq + j * 4) = h;
  }
}

// ---- pass 1b: w_q = (f16) w ------------------------------------------------
__global__ void cvt_w_kernel(const float* __restrict__ w, _Float16* __restrict__ wq,
                             long n4) {
  long i = (long)blockIdx.x * blockDim.x + threadIdx.x;
  long stride = (long)gridDim.x * blockDim.x;
  const float4* w4 = (const float4*)w;
  for (long j = i; j < n4; j += stride) {
    float4 v = w4[j];
    half4v h;
    h[0] = (_Float16)v.x; h[1] = (_Float16)v.y;
    h[2] = (_Float16)v.z; h[3] = (_Float16)v.w;
    *(half4v*)(wq + j * 4) = h;
  }
}

// ---- pass 2: 256^2 8-phase GEMM --------------------------------------------
__global__ __launch_bounds__(512, 2)
void gemm256_8p(const _Float16* __restrict__ A, const _Float16* __restrict__ B,
                const float* __restrict__ bias, const float* __restrict__ is_ptr,
                const float* __restrict__ ws_ptr, float* __restrict__ out,
                int M, int N, int K) {
  // [buf][ksub][row][32k] f16 : 2*2*256*32*2B = 32 KiB per matrix-buf; 128 KiB total
  __shared__ __align__(16) _Float16 sA[2][2][256 * 32];
  __shared__ __align__(16) _Float16 sB[2][2][256 * 32];

  const int nbn = N / BN;
  const int nwg = gridDim.x;
  int wg = blockIdx.x;
  if ((nwg & 7) == 0) {               // bijective XCD swizzle (8 XCDs)
    int q = nwg >> 3;
    wg = (wg & 7) * q + (wg >> 3);
  }
  const int brow = (wg / nbn) * BM;
  const int bcol = (wg % nbn) * BN;

  const int tid  = threadIdx.x;
  const int lane = tid & 63;
  const int w    = tid >> 6;          // wave 0..7
  const int wr   = w >> 2;            // 0..1 : rows [wr*128, +128)
  const int wc   = w & 3;             // 0..3 : cols [wc*64, +64)

  f32x4 accL[4][4] = {};              // m-frags 0..3  (rows +0..63)
  f32x4 accH[4][4] = {};              // m-frags 4..7  (rows +64..127)

  // stage one half-tile (256 rows x 32 k = 16 KiB): 2 x global_load_lds/thread
  auto stageA = [&](int buf, int s, int kt) {
#pragma unroll
    for (int i = 0; i < 2; ++i) {
      int c = i * 512 + tid;                   // 16B chunk 0..1023
      int row = c >> 2, ko = (c & 3) * 8;      // 4 chunks per 64B row
      gload_lds16(A + (size_t)(brow + row) * K + kt + s * 32 + ko,
                  &sA[buf][s][(size_t)(i * 512 + w * 64) * 8]);
    }
  };
  auto stageB = [&](int buf, int s, int kt) {
#pragma unroll
    for (int i = 0; i < 2; ++i) {
      int c = i * 512 + tid;
      int row = c >> 2, ko = (c & 3) * 8;
      gload_lds16(B + (size_t)(bcol + row) * K + kt + s * 32 + ko,
                  &sB[buf][s][(size_t)(i * 512 + w * 64) * 8]);
    }
  };
  // frag reads: row = base + (lane&15), kbyte = (lane>>4)*16 -> wave covers a
  // contiguous 1KB block (each 16B slot exactly once) = bank-even ds_read_b128
  auto ldA = [&](int cb, int s, int mb, half8* a) {
    const _Float16* p =
        &sA[cb][s][(size_t)(wr * 128 + mb * 16 + (lane & 15)) * 32 + (lane >> 4) * 8];
#pragma unroll
    for (int m = 0; m < 4; ++m) a[m] = *(const half8*)(p + m * 512);
  };
  auto ldB = [&](int cb, int s, half8* b) {
    const _Float16* p =
        &sB[cb][s][(size_t)(wc * 64 + (lane & 15)) * 32 + (lane >> 4) * 8];
#pragma unroll
    for (int n = 0; n < 4; ++n) b[n] = *(const half8*)(p + n * 512);
  };

  // ---- prologue: tile 0 -> buf 0. After wait: k0 done, k1 (4 loads) in flight.
  stageA(0, 0, 0); stageB(0, 0, 0);
  stageA(0, 1, 0); stageB(0, 1, 0);
  WAIT_VM(4);
  BAR();

  const int NT = K / BK;
  int cur = 0;
  for (int t = 0; t < NT - 1; ++t) {
    const int nxt = cur ^ 1;
    const int ktn = (t + 1) * BK;
    half8 a[4], b[4];
    // p1: k0 x m0-3 (8 ds_read) | stage A-k0(t+1)
    ldA(cur, 0, 0, a); ldB(cur, 0, b);
    stageA(nxt, 0, ktn);
    BAR();
    MFMA16(a, b, accL);
    BAR();
    // p2: k0 x m4-7 (4 ds_read, reuse b) | stage B-k0(t+1) | vmcnt(4): k1(t) ready
    ldA(cur, 0, 4, a);
    stageB(nxt, 0, ktn);
    BAR();
    MFMA16(a, b, accH);
    WAIT_VM(4);
    BAR();
    // p3: k1 x m0-3 | stage A-k1(t+1)
    ldA(cur, 1, 0, a); ldB(cur, 1, b);
    stageA(nxt, 1, ktn);
    BAR();
    MFMA16(a, b, accL);
    BAR();
    // p4: k1 x m4-7 | stage B-k1(t+1) | vmcnt(4): k0(t+1) ready, k1(t+1) in flight
    ldA(cur, 1, 4, a);
    stageB(nxt, 1, ktn);
    BAR();
    MFMA16(a, b, accH);
    WAIT_VM(4);
    BAR();
    cur = nxt;
  }
  // ---- last tile: no prefetch; drain k1 loads (the only outstanding) at p2.
  {
    half8 a[4], b[4];
    ldA(cur, 0, 0, a); ldB(cur, 0, b);
    BAR();
    MFMA16(a, b, accL);
    BAR();
    ldA(cur, 0, 4, a);
    BAR();
    MFMA16(a, b, accH);
    WAIT_VM(0);
    BAR();
    ldA(cur, 1, 0, a); ldB(cur, 1, b);
    BAR();
    MFMA16(a, b, accL);
    BAR();
    ldA(cur, 1, 4, a);
    MFMA16(a, b, accH);
  }

  // ---- epilogue: C/D 16x16 layout: col = lane&15, row = (lane>>4)*4 + r
  const float sc = is_ptr[0] * ws_ptr[0];
  const int orow = brow + wr * 128;
  const int ocol = bcol + wc * 64;
#pragma unroll
  for (int n = 0; n < 4; ++n) {
    const int col = ocol + n * 16 + (lane & 15);
    const float bv = bias[col];
#pragma unroll
    for (int m = 0; m < 4; ++m) {
#pragma unroll
      for (int r = 0; r < 4; ++r) {
        const int row = orow + m * 16 + (lane >> 4) * 4 + r;
        out[(size_t)row * N + col] = accL[m][n][r] * sc + bv;
        out[(size_t)(row + 64) * N + col] = accH[m][n][r] * sc + bv;
      }
    }
  }
}

// ---------------------------------------------------------------------------
extern "C" void kernel_launch(void* const* d_in, const int* in_sizes, int n_in,
                              void* d_out, int out_size, void* d_ws, size_t ws_size,
                              hipStream_t stream) {
  const float* x    = (const float*)d_in[0];
  const float* wgt  = (const float*)d_in[1];
  const float* bias = (const float*)d_in[2];
  const float* is   = (const float*)d_in[3];
  const float* wsc  = (const float*)d_in[4];
  float* out = (float*)d_out;

  const long x_n = in_sizes[0];
  const long w_n = in_sizes[1];
  const int  N   = in_sizes[2];
  const int  K   = (int)(w_n / N);
  const int  M   = (int)(x_n / K);

  _Float16* xq = (_Float16*)d_ws;
  _Float16* wq = xq + x_n;

  cvt_x_kernel<<<2048, 256, 0, stream>>>(x, xq, is, x_n >> 2);
  cvt_w_kernel<<<2048, 256, 0, stream>>>(wgt, wq, w_n >> 2);

  const int nwg = (M / BM) * (N / BN);   // 32 * 64 = 2048, %8 == 0
  gemm256_8p<<<nwg, 512, 0, stream>>>(xq, wq, bias, is, wsc, out, M, N, K);
}

// Round 3
// 1365.403 us; speedup vs baseline: 1.1911x; 1.1006x over previous
//
#include <hip/hip_runtime.h>
#include <stdint.h>
#include <stddef.h>

// ---------------------------------------------------------------------------
// fp8-fake-quant linear: out = clip(x/s_in, +-448) @ W^T * (s_in*s_w) + bias
// M=8192 K=4096 N=16384. f16 operands (measured absmax 0.0156 vs 0.075 thr).
// Round 3: 256x256 tile, BK=32, 8 waves (2Mx4N).
//  - FRAGMENT-ORDERED LDS: each MFMA wave-fragment stored as a contiguous
//    1KB block lds[buf][blk][lane*16B]. Staging pre-permutes via per-lane
//    GLOBAL addresses (global_load_lds: global side is per-lane, LDS side is
//    wave-uniform base + lane*16). ds_read_b128 is then contiguous-1KB =
//    2-way bank alias = free (fixes the 8-way conflict of round 2).
//  - RING OF 4 K-tile buffers (4 x 32KB = 128KB LDS): stage tile t+3 during
//    tile t -> ~1000+cyc HBM latency cover; one counted vmcnt(8) per K-tile
//    (T3+T4), setprio around MFMA clusters (T5), XCD swizzle (T1).
// ---------------------------------------------------------------------------

typedef _Float16 half8 __attribute__((ext_vector_type(8)));
typedef _Float16 half4v __attribute__((ext_vector_type(4)));
typedef float f32x4 __attribute__((ext_vector_type(4)));

#define BM 256
#define BN 256
#define BK 32
#define NBUF 4
#define FP8MAX 448.0f

__device__ __forceinline__ void gload_lds16(const _Float16* g, _Float16* lds) {
  __builtin_amdgcn_global_load_lds(
      (const __attribute__((address_space(1))) uint32_t*)g,
      (__attribute__((address_space(3))) uint32_t*)lds, 16, 0, 0);
}

#define BAR() asm volatile("s_barrier" ::: "memory")
#define WAIT_VM(N) asm volatile("s_waitcnt vmcnt(" #N ")" ::: "memory")
#define LGKM0() asm volatile("s_waitcnt lgkmcnt(0)" ::: "memory")

#define MFMA16(AF, BF, ACC) do {                                              \
  __builtin_amdgcn_s_setprio(1);                                              \
  _Pragma("unroll")                                                           \
  for (int m_ = 0; m_ < 4; ++m_) {                                            \
    _Pragma("unroll")                                                         \
    for (int n_ = 0; n_ < 4; ++n_)                                            \
      ACC[m_][n_] = __builtin_amdgcn_mfma_f32_16x16x32_f16(                   \
          AF[m_], BF[n_], ACC[m_][n_], 0, 0, 0);                              \
  }                                                                           \
  __builtin_amdgcn_s_setprio(0);                                              \
} while (0)

// ---- pass 1a: x_q = (f16) clip(x / s_in, +-448) ----------------------------
__global__ void cvt_x_kernel(const float* __restrict__ x, _Float16* __restrict__ xq,
                             const float* __restrict__ s_ptr, long n4) {
  float inv = 1.0f / s_ptr[0];
  long i = (long)blockIdx.x * blockDim.x + threadIdx.x;
  long stride = (long)gridDim.x * blockDim.x;
  const float4* x4 = (const float4*)x;
  for (long j = i; j < n4; j += stride) {
    float4 v = x4[j];
    half4v h;
    h[0] = (_Float16)fminf(fmaxf(v.x * inv, -FP8MAX), FP8MAX);
    h[1] = (_Float16)fminf(fmaxf(v.y * inv, -FP8MAX), FP8MAX);
    h[2] = (_Float16)fminf(fmaxf(v.z * inv, -FP8MAX), FP8MAX);
    h[3] = (_Float16)fminf(fmaxf(v.w * inv, -FP8MAX), FP8MAX);
    *(half4v*)(xq + j * 4) = h;
  }
}

// ---- pass 1b: w_q = (f16) w -------------------------------------------------
__global__ void cvt_w_kernel(const float* __restrict__ w, _Float16* __restrict__ wq,
                             long n4) {
  long i = (long)blockIdx.x * blockDim.x + threadIdx.x;
  long stride = (long)gridDim.x * blockDim.x;
  const float4* w4 = (const float4*)w;
  for (long j = i; j < n4; j += stride) {
    float4 v = w4[j];
    half4v h;
    h[0] = (_Float16)v.x; h[1] = (_Float16)v.y;
    h[2] = (_Float16)v.z; h[3] = (_Float16)v.w;
    *(half4v*)(wq + j * 4) = h;
  }
}

// ---- pass 2: 256^2 fragment-LDS ring-4 GEMM ---------------------------------
__global__ __launch_bounds__(512, 2)
void gemm256_fr(const _Float16* __restrict__ A, const _Float16* __restrict__ B,
                const float* __restrict__ bias, const float* __restrict__ is_ptr,
                const float* __restrict__ ws_ptr, float* __restrict__ out,
                int M, int N, int K) {
  // 32 blocks/tile: A blocks 0..15 = (half h)*8 + mfrag, B blocks 16..31 =
  // 16 + (quarter q)*4 + nfrag. Block = 64 lanes x 16B = 512 f16 = 1KB.
  __shared__ __align__(16) _Float16 lds[NBUF][32][512];

  const int nbn = N / BN;
  const int nwg = gridDim.x;
  int wg = blockIdx.x;
  if ((nwg & 7) == 0) {               // bijective XCD swizzle (8 XCDs)
    int q = nwg >> 3;
    wg = (wg & 7) * q + (wg >> 3);
  }
  const int brow = (wg / nbn) * BM;
  const int bcol = (wg % nbn) * BN;

  const int tid  = threadIdx.x;
  const int lane = tid & 63;
  const int w    = tid >> 6;          // wave 0..7
  const int wr   = w >> 2;            // 0..1 : rows [wr*128, +128)
  const int wc   = w & 3;             // 0..3 : cols [wc*64, +64)

  // per-lane global offset inside a fragment block: row (lane&15), k (lane>>4)*8
  const size_t laneoff = (size_t)(lane & 15) * K + (size_t)(lane >> 4) * 8;
  const int blk0 = w * 4;             // this wave stages blocks blk0..blk0+3
  const _Float16* gsrc[4];
#pragma unroll
  for (int j = 0; j < 4; ++j) {
    int b = blk0 + j;
    if (b < 16)
      gsrc[j] = A + (size_t)(brow + (b >> 3) * 128 + (b & 7) * 16) * K + laneoff;
    else
      gsrc[j] = B + (size_t)(bcol + ((b - 16) >> 2) * 64 + ((b - 16) & 3) * 16) * K + laneoff;
  }

  auto stage2 = [&](int tb, int kt, int j0) {
#pragma unroll
    for (int j = 0; j < 2; ++j)
      gload_lds16(gsrc[j0 + j] + kt, &lds[tb][blk0 + j0 + j][0]);
  };

  f32x4 accL[4][4] = {};              // m-frags 0..3  (rows +0..63)
  f32x4 accH[4][4] = {};              // m-frags 4..7  (rows +64..127)

  const int NT = K / BK;              // 128

  // ---- prologue: stage tiles 0,1,2 (12 loads/thread); tile 0 ready after wait
  stage2(0, 0, 0);      stage2(0, 0, 2);
  stage2(1, BK, 0);     stage2(1, BK, 2);
  stage2(2, 2 * BK, 0); stage2(2, 2 * BK, 2);
  WAIT_VM(8);
  BAR();

  for (int t = 0; t < NT; ++t) {
    const int cur = t & 3;
    const bool pf = (t + 3) < NT;
    const int pb = (t + 3) & 3;
    const int pk = (t + 3) * BK;
    half8 a[4], b[4];

    // ---- phase 1: frags m0-3 (+ all B frags, kept for phase 2)
#pragma unroll
    for (int m = 0; m < 4; ++m) a[m] = *(const half8*)&lds[cur][wr * 8 + m][lane * 8];
#pragma unroll
    for (int n = 0; n < 4; ++n) b[n] = *(const half8*)&lds[cur][16 + wc * 4 + n][lane * 8];
    if (pf) stage2(pb, pk, 0);
    BAR();
    LGKM0();
    MFMA16(a, b, accL);
    BAR();

    // ---- phase 2: frags m4-7 (B reused from registers)
#pragma unroll
    for (int m = 0; m < 4; ++m) a[m] = *(const half8*)&lds[cur][wr * 8 + 4 + m][lane * 8];
    if (pf) stage2(pb, pk, 2);
    BAR();
    LGKM0();
    MFMA16(a, b, accH);
    // tile-end counted wait: tile t+1's 4 loads (issued at t-2) must be done
    if (t < NT - 3)       WAIT_VM(8);
    else if (t == NT - 3) WAIT_VM(4);
    else if (t == NT - 2) WAIT_VM(0);
    BAR();
  }

  // ---- epilogue: C/D 16x16 layout: col = lane&15, row = (lane>>4)*4 + r
  const float sc = is_ptr[0] * ws_ptr[0];
  const int orow = brow + wr * 128;
  const int ocol = bcol + wc * 64;
#pragma unroll
  for (int n = 0; n < 4; ++n) {
    const int col = ocol + n * 16 + (lane & 15);
    const float bv = bias[col];
#pragma unroll
    for (int m = 0; m < 4; ++m) {
#pragma unroll
      for (int r = 0; r < 4; ++r) {
        const int row = orow + m * 16 + (lane >> 4) * 4 + r;
        out[(size_t)row * N + col] = accL[m][n][r] * sc + bv;
        out[(size_t)(row + 64) * N + col] = accH[m][n][r] * sc + bv;
      }
    }
  }
}

// ---------------------------------------------------------------------------
extern "C" void kernel_launch(void* const* d_in, const int* in_sizes, int n_in,
                              void* d_out, int out_size, void* d_ws, size_t ws_size,
                              hipStream_t stream) {
  const float* x    = (const float*)d_in[0];
  const float* wgt  = (const float*)d_in[1];
  const float* bias = (const float*)d_in[2];
  const float* is   = (const float*)d_in[3];
  const float* wsc  = (const float*)d_in[4];
  float* out = (float*)d_out;

  const long x_n = in_sizes[0];
  const long w_n = in_sizes[1];
  const int  N   = in_sizes[2];
  const int  K   = (int)(w_n / N);
  const int  M   = (int)(x_n / K);

  _Float16* xq = (_Float16*)d_ws;
  _Float16* wq = xq + x_n;

  cvt_x_kernel<<<2048, 256, 0, stream>>>(x, xq, is, x_n >> 2);
  cvt_w_kernel<<<2048, 256, 0, stream>>>(wgt, wq, w_n >> 2);

  const int nwg = (M / BM) * (N / BN);   // 32 * 64 = 2048, %8 == 0
  gemm256_fr<<<nwg, 512, 0, stream>>>(xq, wq, bias, is, wsc, out, M, N, K);
}

// Round 4
// 1359.868 us; speedup vs baseline: 1.1959x; 1.0041x over previous
//
#include <hip/hip_runtime.h>
#include <stdint.h>
#include <stddef.h>

// ---------------------------------------------------------------------------
// fp8-fake-quant linear: out = clip(x/s_in, +-448) @ W^T * (s_in*s_w) + bias
// M=8192 K=4096 N=16384. f16 operands (measured absmax 0.0156 vs 0.075 thr).
// Round 4: 256x256 tile, BK=32, 8 waves, fragment-ordered LDS (round 3,
// conflict-free), ring-4 K-tile buffers, and a REGISTER-LEVEL PIPELINE:
//   - ONE barrier per K-tile (ring-4 makes intra-tile barriers unnecessary)
//   - ds_reads for the next MFMA cluster are issued BEFORE the current MFMA
//     cluster, with counted lgkmcnt waits -> LDS pipe overlaps matrix pipe
//   - counted vmcnt(4) per tile (tiles <= t+1 landed before the barrier that
//     opens tile t+1; vmcnt is per-wave so the guarantee rides the barrier)
//   - sched_barrier(0) after counted lgkm waits (rule #18: hipcc hoists
//     register-only MFMA past inline-asm waitcnt otherwise)
// ---------------------------------------------------------------------------

typedef _Float16 half8 __attribute__((ext_vector_type(8)));
typedef _Float16 half4v __attribute__((ext_vector_type(4)));
typedef float f32x4 __attribute__((ext_vector_type(4)));

#define BM 256
#define BN 256
#define BK 32
#define NBUF 4
#define FP8MAX 448.0f

__device__ __forceinline__ void gload_lds16(const _Float16* g, _Float16* lds) {
  __builtin_amdgcn_global_load_lds(
      (const __attribute__((address_space(1))) uint32_t*)g,
      (__attribute__((address_space(3))) uint32_t*)lds, 16, 0, 0);
}

#define BAR() asm volatile("s_barrier" ::: "memory")
#define WAIT_VM(N) asm volatile("s_waitcnt vmcnt(" #N ")" ::: "memory")
#define WAIT_LGKM(N) asm volatile("s_waitcnt lgkmcnt(" #N ")" ::: "memory")
#define SCHED_FENCE() __builtin_amdgcn_sched_barrier(0)

#define MFMA16(AF, BF, ACC) do {                                              \
  __builtin_amdgcn_s_setprio(1);                                              \
  _Pragma("unroll")                                                           \
  for (int m_ = 0; m_ < 4; ++m_) {                                            \
    _Pragma("unroll")                                                         \
    for (int n_ = 0; n_ < 4; ++n_)                                            \
      ACC[m_][n_] = __builtin_amdgcn_mfma_f32_16x16x32_f16(                   \
          AF[m_], BF[n_], ACC[m_][n_], 0, 0, 0);                              \
  }                                                                           \
  __builtin_amdgcn_s_setprio(0);                                              \
} while (0)

// ---- pass 1a: x_q = (f16) clip(x / s_in, +-448) ----------------------------
__global__ void cvt_x_kernel(const float* __restrict__ x, _Float16* __restrict__ xq,
                             const float* __restrict__ s_ptr, long n4) {
  float inv = 1.0f / s_ptr[0];
  long i = (long)blockIdx.x * blockDim.x + threadIdx.x;
  long stride = (long)gridDim.x * blockDim.x;
  const float4* x4 = (const float4*)x;
  for (long j = i; j < n4; j += stride) {
    float4 v = x4[j];
    half4v h;
    h[0] = (_Float16)fminf(fmaxf(v.x * inv, -FP8MAX), FP8MAX);
    h[1] = (_Float16)fminf(fmaxf(v.y * inv, -FP8MAX), FP8MAX);
    h[2] = (_Float16)fminf(fmaxf(v.z * inv, -FP8MAX), FP8MAX);
    h[3] = (_Float16)fminf(fmaxf(v.w * inv, -FP8MAX), FP8MAX);
    *(half4v*)(xq + j * 4) = h;
  }
}

// ---- pass 1b: w_q = (f16) w -------------------------------------------------
__global__ void cvt_w_kernel(const float* __restrict__ w, _Float16* __restrict__ wq,
                             long n4) {
  long i = (long)blockIdx.x * blockDim.x + threadIdx.x;
  long stride = (long)gridDim.x * blockDim.x;
  const float4* w4 = (const float4*)w;
  for (long j = i; j < n4; j += stride) {
    float4 v = w4[j];
    half4v h;
    h[0] = (_Float16)v.x; h[1] = (_Float16)v.y;
    h[2] = (_Float16)v.z; h[3] = (_Float16)v.w;
    *(half4v*)(wq + j * 4) = h;
  }
}

// ---- pass 2: 256^2 fragment-LDS ring-4 reg-pipelined GEMM -------------------
__global__ __launch_bounds__(512, 2)
void gemm256_rp(const _Float16* __restrict__ A, const _Float16* __restrict__ B,
                const float* __restrict__ bias, const float* __restrict__ is_ptr,
                const float* __restrict__ ws_ptr, float* __restrict__ out,
                int M, int N, int K) {
  // 32 blocks/tile: A blocks 0..15 = (half)*8 + mfrag, B blocks 16..31 =
  // 16 + (quarter)*4 + nfrag. Block = 64 lanes x 16B = 512 f16 = 1KB.
  __shared__ __align__(16) _Float16 lds[NBUF][32][512];

  const int nbn = N / BN;
  const int nwg = gridDim.x;
  int wg = blockIdx.x;
  if ((nwg & 7) == 0) {               // bijective XCD swizzle (8 XCDs)
    int q = nwg >> 3;
    wg = (wg & 7) * q + (wg >> 3);
  }
  const int brow = (wg / nbn) * BM;
  const int bcol = (wg % nbn) * BN;

  const int tid  = threadIdx.x;
  const int lane = tid & 63;
  const int w    = tid >> 6;          // wave 0..7
  const int wr   = w >> 2;            // 0..1 : rows [wr*128, +128)
  const int wc   = w & 3;             // 0..3 : cols [wc*64, +64)

  // per-lane global offset inside a fragment block: row (lane&15), k (lane>>4)*8
  const size_t laneoff = (size_t)(lane & 15) * K + (size_t)(lane >> 4) * 8;
  const int blk0 = w * 4;             // this wave stages blocks blk0..blk0+3
  const _Float16* gsrc[4];
#pragma unroll
  for (int j = 0; j < 4; ++j) {
    int b = blk0 + j;
    if (b < 16)
      gsrc[j] = A + (size_t)(brow + (b >> 3) * 128 + (b & 7) * 16) * K + laneoff;
    else
      gsrc[j] = B + (size_t)(bcol + ((b - 16) >> 2) * 64 + ((b - 16) & 3) * 16) * K + laneoff;
  }

  auto stage = [&](int tb, int kt) {
#pragma unroll
    for (int j = 0; j < 4; ++j)
      gload_lds16(gsrc[j] + kt, &lds[tb][blk0 + j][0]);
  };

  f32x4 accL[4][4] = {};              // m-frags 0..3  (rows +0..63)
  f32x4 accH[4][4] = {};              // m-frags 4..7  (rows +64..127)

  const int NT = K / BK;              // 128 (even; loop unrolled by 2)

  // tile body: entry regs AC/BC = (t,p1) frags, valid; tiles t,t+1 landed;
  // outstanding vmem = {t+2}. Exits with AN/BN_ = (t+1,p1) valid.
  auto tile_body = [&](int t, half8 (&AC)[4], half8 (&BC)[4],
                       half8 (&AN)[4], half8 (&BN_)[4]) {
    const int cb = t & 3, nb = (t + 1) & 3;
    const bool pf = (t + 3) < NT;
    half8 AH[4];
    if (pf) stage((t + 3) & 3, (t + 3) * BK);          // vm: 4 -> 8
    // issue (t,p2) reads; covered by MFMA(AC)
#pragma unroll
    for (int m = 0; m < 4; ++m)
      AH[m] = *(const half8*)&lds[cb][wr * 8 + 4 + m][lane * 8];
    MFMA16(AC, BC, accL);
    // issue (t+1,p1) reads; covered by MFMA(AH)
#pragma unroll
    for (int m = 0; m < 4; ++m)
      AN[m] = *(const half8*)&lds[nb][wr * 8 + m][lane * 8];
#pragma unroll
    for (int n = 0; n < 4; ++n)
      BN_[n] = *(const half8*)&lds[nb][16 + wc * 4 + n][lane * 8];
    WAIT_LGKM(8);                       // AH retired (oldest 4 of 12)
    SCHED_FENCE();
    MFMA16(AH, BC, accH);
    WAIT_LGKM(0);                       // AN/BN_ retired
    SCHED_FENCE();
    if (pf) { WAIT_VM(4); } else { WAIT_VM(0); }   // tiles <= t+2 landed
    BAR();                              // opens tile t+1 (and buf reuse)
  };

  // ---- prologue: stage tiles 0,1,2; preload (0,p1) regs
  stage(0, 0);
  stage(1, BK);
  stage(2, 2 * BK);
  WAIT_VM(4);                           // tiles 0,1 landed ({2} outstanding)
  BAR();

  half8 aP[4], bP[4], aQ[4], bQ[4];
#pragma unroll
  for (int m = 0; m < 4; ++m) aP[m] = *(const half8*)&lds[0][wr * 8 + m][lane * 8];
#pragma unroll
  for (int n = 0; n < 4; ++n) bP[n] = *(const half8*)&lds[0][16 + wc * 4 + n][lane * 8];
  WAIT_LGKM(0);
  SCHED_FENCE();

  for (int t = 0; t < NT; t += 2) {
    tile_body(t,     aP, bP, aQ, bQ);
    tile_body(t + 1, aQ, bQ, aP, bP);
  }

  // ---- epilogue: C/D 16x16 layout: col = lane&15, row = (lane>>4)*4 + r
  const float sc = is_ptr[0] * ws_ptr[0];
  const int orow = brow + wr * 128;
  const int ocol = bcol + wc * 64;
#pragma unroll
  for (int n = 0; n < 4; ++n) {
    const int col = ocol + n * 16 + (lane & 15);
    const float bv = bias[col];
#pragma unroll
    for (int m = 0; m < 4; ++m) {
#pragma unroll
      for (int r = 0; r < 4; ++r) {
        const int row = orow + m * 16 + (lane >> 4) * 4 + r;
        out[(size_t)row * N + col] = accL[m][n][r] * sc + bv;
        out[(size_t)(row + 64) * N + col] = accH[m][n][r] * sc + bv;
      }
    }
  }
}

// ---------------------------------------------------------------------------
extern "C" void kernel_launch(void* const* d_in, const int* in_sizes, int n_in,
                              void* d_out, int out_size, void* d_ws, size_t ws_size,
                              hipStream_t stream) {
  const float* x    = (const float*)d_in[0];
  const float* wgt  = (const float*)d_in[1];
  const float* bias = (const float*)d_in[2];
  const float* is   = (const float*)d_in[3];
  const float* wsc  = (const float*)d_in[4];
  float* out = (float*)d_out;

  const long x_n = in_sizes[0];
  const long w_n = in_sizes[1];
  const int  N   = in_sizes[2];
  const int  K   = (int)(w_n / N);
  const int  M   = (int)(x_n / K);

  _Float16* xq = (_Float16*)d_ws;
  _Float16* wq = xq + x_n;

  cvt_x_kernel<<<2048, 256, 0, stream>>>(x, xq, is, x_n >> 2);
  cvt_w_kernel<<<2048, 256, 0, stream>>>(wgt, wq, w_n >> 2);

  const int nwg = (M / BM) * (N / BN);   // 32 * 64 = 2048, %8 == 0
  gemm256_rp<<<nwg, 512, 0, stream>>>(xq, wq, bias, is, wsc, out, M, N, K);
}